// Round 4
// baseline (165.458 us; speedup 1.0000x reference)
//
#include <hip/hip_runtime.h>
#include <math.h>

#define EDIM   1024
#define KVEDIM 256
#define HDIM   64
#define QHEADS 16

typedef __attribute__((ext_vector_type(8))) short short8;   // 8 bf16 (4 VGPRs)
typedef __attribute__((ext_vector_type(4))) float f32x4;

// fp32 -> bf16 (RNE)
__device__ __forceinline__ short f2b(float a) {
    unsigned ua = __builtin_bit_cast(unsigned, a);
    ua += 0x7fffu + ((ua >> 16) & 1u);
    return (short)(ua >> 16);
}
// packed RNE f32->bf16 pair in one instruction
__device__ __forceinline__ unsigned cvtpk(float a, float b) {
    unsigned r;
    asm("v_cvt_pk_bf16_f32 %0, %1, %2" : "=v"(r) : "v"(a), "v"(b));
    return r;
}

// ---------------------------------------------------------------------------
// Fused-convert projection GEMM: C[M,N] = (A[M,K] @ W[N,K]^T + bias) * scale,
// A and W read as fp32 and converted to bf16 in-register during staging
// (v_cvt_pk_bf16_f32 = same RNE rounding as the old separate cvt pass).
// 64x64 tile, BK=64, 256 threads (4 waves, each 32x32 via 2x2 MFMA tiles).
// Grid decode: [0,512) = q (32x16), [512,640) = k, [640,768) = v (32x4).
// 768 blocks = 3 blocks/CU (vs 192 = <1/CU at 128x128) -- occupancy was the
// bottleneck: latency-bound GEMM at 4 waves/CU.
// ---------------------------------------------------------------------------
__global__ __launch_bounds__(256)
void proj_gemm(const float* __restrict__ Aq, const float* __restrict__ Ak,
               const float* __restrict__ Av,
               const float* __restrict__ Wqf, const float* __restrict__ Wkf,
               const float* __restrict__ Wvf,
               const float* __restrict__ bq, const float* __restrict__ bk,
               const float* __restrict__ bv,
               short* __restrict__ Cq, short* __restrict__ Ck,
               short* __restrict__ Cv, float qscale)
{
    const int bid = blockIdx.x;
    const float* A; const float* W; const float* bias; short* C;
    int N, bm, bn; float scale;
    if (bid < 512) {
        A = Aq; W = Wqf; bias = bq; C = Cq; N = EDIM; scale = qscale;
        bm = (bid >> 4) * 64; bn = (bid & 15) * 64;
    } else if (bid < 640) {
        int i = bid - 512;
        A = Ak; W = Wkf; bias = bk; C = Ck; N = KVEDIM; scale = 1.0f;
        bm = (i >> 2) * 64; bn = (i & 3) * 64;
    } else {
        int i = bid - 640;
        A = Av; W = Wvf; bias = bv; C = Cv; N = KVEDIM; scale = 1.0f;
        bm = (i >> 2) * 64; bn = (i & 3) * 64;
    }
    const int K = EDIM;

    __shared__ short As[64 * 72];
    __shared__ short Ws[64 * 72];

    const int t = threadIdx.x, lane = t & 63, wv = t >> 6;
    const int lm = lane & 15, quad = lane >> 4;
    const int q8 = quad * 8, q4 = quad * 4;
    const int wm = (wv & 1) * 32, wn = (wv >> 1) * 32;
    const int sr = t >> 2, c0 = (t & 3) * 16;   // staging: row, 16-float col base

    const f32x4 zero = {0.f, 0.f, 0.f, 0.f};
    f32x4 acc[2][2] = {{zero, zero}, {zero, zero}};

    for (int k0 = 0; k0 < K; k0 += 64) {
        __syncthreads();
        {
            const float4* ap = (const float4*)&A[(size_t)(bm + sr) * K + k0 + c0];
            float4 a0 = ap[0], a1 = ap[1], a2 = ap[2], a3 = ap[3];
            uint4 o0, o1;
            o0.x = cvtpk(a0.x, a0.y); o0.y = cvtpk(a0.z, a0.w);
            o0.z = cvtpk(a1.x, a1.y); o0.w = cvtpk(a1.z, a1.w);
            o1.x = cvtpk(a2.x, a2.y); o1.y = cvtpk(a2.z, a2.w);
            o1.z = cvtpk(a3.x, a3.y); o1.w = cvtpk(a3.z, a3.w);
            *(uint4*)&As[sr * 72 + c0]     = o0;
            *(uint4*)&As[sr * 72 + c0 + 8] = o1;
            const float4* wp = (const float4*)&W[(size_t)(bn + sr) * K + k0 + c0];
            float4 w0 = wp[0], w1 = wp[1], w2 = wp[2], w3 = wp[3];
            uint4 p0, p1;
            p0.x = cvtpk(w0.x, w0.y); p0.y = cvtpk(w0.z, w0.w);
            p0.z = cvtpk(w1.x, w1.y); p0.w = cvtpk(w1.z, w1.w);
            p1.x = cvtpk(w2.x, w2.y); p1.y = cvtpk(w2.z, w2.w);
            p1.z = cvtpk(w3.x, w3.y); p1.w = cvtpk(w3.z, w3.w);
            *(uint4*)&Ws[sr * 72 + c0]     = p0;
            *(uint4*)&Ws[sr * 72 + c0 + 8] = p1;
        }
        __syncthreads();
        #pragma unroll
        for (int ks = 0; ks < 2; ++ks) {
            short8 af[2], bfr[2];
            #pragma unroll
            for (int i = 0; i < 2; ++i)
                af[i] = *(const short8*)&As[(wm + i * 16 + lm) * 72 + ks * 32 + q8];
            #pragma unroll
            for (int j = 0; j < 2; ++j)
                bfr[j] = *(const short8*)&Ws[(wn + j * 16 + lm) * 72 + ks * 32 + q8];
            #pragma unroll
            for (int i = 0; i < 2; ++i)
                #pragma unroll
                for (int j = 0; j < 2; ++j)
                    acc[i][j] = __builtin_amdgcn_mfma_f32_16x16x32_bf16(
                        af[i], bfr[j], acc[i][j], 0, 0, 0);
        }
    }

    #pragma unroll
    for (int j = 0; j < 2; ++j) {
        float bj = bias[bn + wn + j * 16 + lm];
        #pragma unroll
        for (int i = 0; i < 2; ++i)
            #pragma unroll
            for (int r = 0; r < 4; ++r)
                C[(size_t)(bm + wm + i * 16 + q4 + r) * N + bn + wn + j * 16 + lm] =
                    f2b((acc[i][j][r] + bj) * scale);
    }
}

// ---------------------------------------------------------------------------
// MFMA flash attention. Block = 16 q-rows x 4 q-heads (one wave per q-head),
// sharing one KV head; blockIdx.z = KV split (associative no-max exp2
// softmax -> unnormalized partials combined in ln_kernel).
//
// Round-4: DOUBLE-BUFFERED K/V LDS, ONE barrier per 64-key chunk (was 2).
//   iter t: [issue global loads t+1] -> barrier -> [compute buf[cur]]
//           -> [write regs -> buf[cur^1]] -> swap.
//   Safety: writes at t touch buf[nxt], last read at t-1 BEFORE the iter-t
//   barrier; reads at t touch buf[cur], written at t-1 before the same
//   barrier. Prefetch slack grows to a full chunk (≥ L2 latency).
//
// QK^T operand-swapped (S' = K.Q^T): lane(lm,quad) reg r holds
// P[qrow=lm][key=kt*16+quad*4+r] == A-frag slot (quad, elem). PV packs two
// 16-key tiles into one full-K mfma_f32_16x16x32 (A(quad,e)*B(quad,e) is
// layout-robust); V staged element-matched:
//   Vs slot = dt*128 + ktp*64 + quad*16 + lm, elems half*4+j
// Ks ([64][64]) and Vs use slot-XOR involution slot ^= (slot>>4)&7 (16B
// slots): all accesses bank-uniform or 2-way (SQ_LDS_BANK_CONFLICT == 0,
// measured r3). P never touches LDS; no cross-wave reductions.
// ---------------------------------------------------------------------------
__global__ __launch_bounds__(256, 4)
void attn_mfma(const short* __restrict__ q, const short* __restrict__ k,
               const short* __restrict__ v, float* __restrict__ x,
               float* __restrict__ opart, float* __restrict__ lpart,
               int n, int s_len, int partial)
{
    __shared__ short Ks[2][64 * 64];   // K chunk [s][d], swizzled (2 x 8 KB)
    __shared__ short Vs[2][4096];      // V chunk, PV-frag layout  (2 x 8 KB)

    const int kvh = blockIdx.y;
    const int r0  = blockIdx.x * 16;
    const int t = threadIdx.x, lane = t & 63, wv = t >> 6;
    const int qh = (kvh << 2) | wv;          // wave's q-head
    const int lm = lane & 15, quad = lane >> 4, q8 = quad * 8;

    // Q B-fragments for this wave's 16 q-rows (reused every chunk)
    short8 qf0, qf1;
    {
        const short* qp = &q[(size_t)(r0 + lm) * EDIM + qh * HDIM];
        qf0 = *(const short8*)&qp[q8];
        qf1 = *(const short8*)&qp[32 + q8];
    }

    const f32x4 zero = {0.f, 0.f, 0.f, 0.f};
    f32x4 oacc[4] = {zero, zero, zero, zero};   // O[qrow=quad*4+r][d=dt*16+lm]
    float lp = 0.f;

    // staging maps
    const int sr  = t >> 2;                  // K source row (0..63)
    const int scs = (t & 3) * 16;            // K col base (shorts)
    const int kw0 = sr * 64 + (scs ^ ((sr & 7) << 3));
    const int kw1 = sr * 64 + ((scs + 8) ^ ((sr & 7) << 3));
    const int vs4 = (t & 15) * 4;            // V: s-block
    const int vd0 = (t >> 4) * 4;            // V: d-block
    const int vktp = vs4 >> 5, vqd = (vs4 >> 2) & 3, vhf = (vs4 >> 4) & 1;

    // QK read column offsets (swizzled)
    const int krx  = q8 ^ ((lm & 7) << 3);
    const int krx2 = (32 + q8) ^ ((lm & 7) << 3);

    const int s_lo = (int)blockIdx.z * s_len;
    const int nt = s_len >> 6;
    const size_t kbase = (size_t)kvh * HDIM;

    uint4 kra, krb;
    uint2 vrr[4];

    // ---- prologue: load chunk 0, write buf 0 ----
    {
        const uint4* ks = (const uint4*)&k[(size_t)(s_lo + sr) * KVEDIM + kbase + scs];
        kra = ks[0]; krb = ks[1];
        #pragma unroll
        for (int i = 0; i < 4; ++i)
            vrr[i] = *(const uint2*)&v[(size_t)(s_lo + vs4 + i) * KVEDIM + kbase + vd0];
    }
    {
        *(uint4*)&Ks[0][kw0] = kra;
        *(uint4*)&Ks[0][kw1] = krb;
        #pragma unroll
        for (int j = 0; j < 4; ++j) {
            const unsigned sel = (j & 1) ? 0x07060302u : 0x05040100u;
            unsigned a0 = (j < 2) ? vrr[0].x : vrr[0].y;
            unsigned a1 = (j < 2) ? vrr[1].x : vrr[1].y;
            unsigned a2 = (j < 2) ? vrr[2].x : vrr[2].y;
            unsigned a3 = (j < 2) ? vrr[3].x : vrr[3].y;
            uint2 o;
            o.x = __builtin_amdgcn_perm(a1, a0, sel);
            o.y = __builtin_amdgcn_perm(a3, a2, sel);
            const int dd = vd0 + j;
            int slot = ((dd >> 4) << 7) + (vktp << 6) + (vqd << 4) + (dd & 15);
            slot ^= (slot >> 4) & 7;
            *(uint2*)&Vs[0][slot * 8 + vhf * 4] = o;
        }
    }

    int cur = 0;
    for (int it = 0; it < nt; ++it) {
        // ---- 1. issue next chunk's global loads (consumed after compute) ----
        if (it + 1 < nt) {
            const int s1 = s_lo + (it + 1) * 64;
            const uint4* ks = (const uint4*)&k[(size_t)(s1 + sr) * KVEDIM + kbase + scs];
            kra = ks[0]; krb = ks[1];
            #pragma unroll
            for (int i = 0; i < 4; ++i)
                vrr[i] = *(const uint2*)&v[(size_t)(s1 + vs4 + i) * KVEDIM + kbase + vd0];
        }

        // ---- 2. single barrier: buf[cur] writes visible, buf[nxt] readers done
        __syncthreads();

        // ---- 3a. S' = K . Q^T ; P kept in registers ----
        uint2 pa[4];
        #pragma unroll
        for (int kt = 0; kt < 4; ++kt) {
            const int krow = (kt * 16 + lm) * 64;
            short8 kf0 = *(const short8*)&Ks[cur][krow + krx];
            short8 kf1 = *(const short8*)&Ks[cur][krow + krx2];
            f32x4 s = zero;
            __builtin_amdgcn_s_setprio(1);
            s = __builtin_amdgcn_mfma_f32_16x16x32_bf16(kf0, qf0, s, 0, 0, 0);
            s = __builtin_amdgcn_mfma_f32_16x16x32_bf16(kf1, qf1, s, 0, 0, 0);
            __builtin_amdgcn_s_setprio(0);
            float p0 = exp2f(s[0]), p1 = exp2f(s[1]);
            float p2 = exp2f(s[2]), p3 = exp2f(s[3]);
            lp += (p0 + p1) + (p2 + p3);
            pa[kt].x = cvtpk(p0, p1);
            pa[kt].y = cvtpk(p2, p3);
        }

        // ---- 3b. O += P . V : full-K=32 MFMAs, A packs two 16-key tiles ----
        uint4 ap0; ap0.x = pa[0].x; ap0.y = pa[0].y; ap0.z = pa[1].x; ap0.w = pa[1].y;
        uint4 ap1; ap1.x = pa[2].x; ap1.y = pa[2].y; ap1.z = pa[3].x; ap1.w = pa[3].y;
        __builtin_amdgcn_s_setprio(1);
        #pragma unroll
        for (int dt = 0; dt < 4; ++dt) {
            int sb  = (dt << 7) + (quad << 4) + lm;       // ktp=0
            int sx0 = sb ^ ((sb >> 4) & 7);
            int sb1 = sb + 64;                            // ktp=1
            int sx1 = sb1 ^ ((sb1 >> 4) & 7);
            oacc[dt] = __builtin_amdgcn_mfma_f32_16x16x32_bf16(
                __builtin_bit_cast(short8, ap0),
                *(const short8*)&Vs[cur][sx0 * 8], oacc[dt], 0, 0, 0);
            oacc[dt] = __builtin_amdgcn_mfma_f32_16x16x32_bf16(
                __builtin_bit_cast(short8, ap1),
                *(const short8*)&Vs[cur][sx1 * 8], oacc[dt], 0, 0, 0);
        }
        __builtin_amdgcn_s_setprio(0);

        // ---- 4. write next chunk into the other buffer ----
        if (it + 1 < nt) {
            const int nxt = cur ^ 1;
            *(uint4*)&Ks[nxt][kw0] = kra;
            *(uint4*)&Ks[nxt][kw1] = krb;
            #pragma unroll
            for (int j = 0; j < 4; ++j) {
                const unsigned sel = (j & 1) ? 0x07060302u : 0x05040100u;
                unsigned a0 = (j < 2) ? vrr[0].x : vrr[0].y;
                unsigned a1 = (j < 2) ? vrr[1].x : vrr[1].y;
                unsigned a2 = (j < 2) ? vrr[2].x : vrr[2].y;
                unsigned a3 = (j < 2) ? vrr[3].x : vrr[3].y;
                uint2 o;
                o.x = __builtin_amdgcn_perm(a1, a0, sel);
                o.y = __builtin_amdgcn_perm(a3, a2, sel);
                const int dd = vd0 + j;
                int slot = ((dd >> 4) << 7) + (vktp << 6) + (vqd << 4) + (dd & 15);
                slot ^= (slot >> 4) & 7;
                *(uint2*)&Vs[nxt][slot * 8 + vhf * 4] = o;
            }
        }
        cur ^= 1;
    }

    // ---- softmax denominator: reduce across quads (same lm = same qrow) ----
    float lt = lp;
    lt += __shfl_xor(lt, 16);
    lt += __shfl_xor(lt, 32);
    // every lane now holds the full l-sum for qrow = lm

    if (partial) {
        float* xp = opart + (size_t)blockIdx.z * n * EDIM;
        if (lane < 16)
            lpart[(size_t)blockIdx.z * n * QHEADS + (size_t)(r0 + lane) * QHEADS + qh] = lt;
        #pragma unroll
        for (int r = 0; r < 4; ++r) {
            const int row = r0 + quad * 4 + r;
            #pragma unroll
            for (int dt = 0; dt < 4; ++dt)
                xp[(size_t)row * EDIM + qh * HDIM + dt * 16 + lm] = oacc[dt][r];
        }
    } else {
        float linv[4];
        #pragma unroll
        for (int r = 0; r < 4; ++r)
            linv[r] = 1.0f / __shfl(lt, quad * 4 + r);
        #pragma unroll
        for (int r = 0; r < 4; ++r) {
            const int row = r0 + quad * 4 + r;
            #pragma unroll
            for (int dt = 0; dt < 4; ++dt)
                x[(size_t)row * EDIM + qh * HDIM + dt * 16 + lm] = oacc[dt][r] * linv[r];
        }
    }
}

// ---------------------------------------------------------------------------
// Split-KV combine (unnormalized O partials / l partials) + LayerNorm.
// nsplit == 0: plain in-place LN on x (fallback path).
// ---------------------------------------------------------------------------
__global__ __launch_bounds__(256)
void ln_kernel(float* __restrict__ x, const float* __restrict__ gamma,
               const float* __restrict__ beta,
               const float* __restrict__ opart, const float* __restrict__ lpart,
               int nsplit, int n)
{
    const int row = blockIdx.x;
    const int t = threadIdx.x;

    float4 xv;
    if (nsplit > 0) {
        const int head = t >> 4;                 // (t*4)/64
        float l = 0.f;
        float4 s = {0.f, 0.f, 0.f, 0.f};
        for (int z = 0; z < nsplit; ++z) {
            const float4 o = *(const float4*)&opart[(size_t)z * n * EDIM +
                                                    (size_t)row * EDIM + t * 4];
            s.x += o.x; s.y += o.y; s.z += o.z; s.w += o.w;
            l += lpart[(size_t)z * n * QHEADS + (size_t)row * QHEADS + head];
        }
        const float inv = 1.f / l;
        xv.x = s.x * inv; xv.y = s.y * inv; xv.z = s.z * inv; xv.w = s.w * inv;
    } else {
        xv = *(const float4*)&x[(size_t)row * EDIM + t * 4];
    }

    float sm  = xv.x + xv.y + xv.z + xv.w;
    float sq = xv.x * xv.x + xv.y * xv.y + xv.z * xv.z + xv.w * xv.w;
    #pragma unroll
    for (int m = 1; m < 64; m <<= 1) {
        sm += __shfl_xor(sm, m);
        sq += __shfl_xor(sq, m);
    }
    __shared__ float ws_[4], wq_[4];
    const int wave = t >> 6;
    if ((t & 63) == 0) { ws_[wave] = sm; wq_[wave] = sq; }
    __syncthreads();
    sm = ws_[0] + ws_[1] + ws_[2] + ws_[3];
    sq = wq_[0] + wq_[1] + wq_[2] + wq_[3];

    const float mu   = sm * (1.f / EDIM);
    const float var  = sq * (1.f / EDIM) - mu * mu;
    const float rstd = rsqrtf(var + 1e-5f);

    float4 g = *(const float4*)&gamma[t * 4];
    float4 b = *(const float4*)&beta[t * 4];
    float4 o;
    o.x = (xv.x - mu) * rstd * g.x + b.x;
    o.y = (xv.y - mu) * rstd * g.y + b.y;
    o.z = (xv.z - mu) * rstd * g.z + b.z;
    o.w = (xv.w - mu) * rstd * g.w + b.w;
    *(float4*)&x[(size_t)row * EDIM + t * 4] = o;
}

// ---------------------------------------------------------------------------
extern "C" void kernel_launch(void* const* d_in, const int* in_sizes, int n_in,
                              void* d_out, int out_size, void* d_ws, size_t ws_size,
                              hipStream_t stream)
{
    const float* query = (const float*)d_in[0];
    const float* key   = (const float*)d_in[1];
    const float* value = (const float*)d_in[2];
    const float* Wq    = (const float*)d_in[3];
    const float* bq    = (const float*)d_in[4];
    const float* Wk    = (const float*)d_in[5];
    const float* bk    = (const float*)d_in[6];
    const float* Wv    = (const float*)d_in[7];
    const float* bv    = (const float*)d_in[8];
    const float* gamma = (const float*)d_in[9];
    const float* beta  = (const float*)d_in[10];
    float* out = (float*)d_out;

    const int n = in_sizes[0] / EDIM;   // 2048

    // workspace layout: projection outputs (bf16), then fp32 split partials
    short* qb  = (short*)d_ws;                 // q proj  n*1024
    short* kb  = qb + (size_t)n * EDIM;        // k proj  n*256
    short* vb  = kb + (size_t)n * KVEDIM;      // v proj  n*256
    short* ws_end = vb + (size_t)n * KVEDIM;

    const size_t base_bytes = (size_t)((char*)ws_end - (char*)d_ws);
    int nsplit = 0;
    {
        const int cand = 2;   // 1024 attn blocks = 4/CU
        size_t need = base_bytes +
                      (size_t)cand * ((size_t)n * EDIM + (size_t)n * QHEADS) * sizeof(float);
        if ((n % (64 * cand)) == 0 && need <= ws_size) nsplit = cand;
    }
    float* opart = (float*)ws_end;
    float* lpart = opart + (size_t)(nsplit > 0 ? nsplit : 1) * n * EDIM;

    // 1/sqrt(64) * log2(e): exp2-based softmax without max subtraction
    const float qscale = 0.125f * 1.44269504088896f;

    proj_gemm<<<dim3(768), 256, 0, stream>>>(
        query, key, value, Wq, Wk, Wv, bq, bk, bv, qb, kb, vb, qscale);

    const int zdim  = (nsplit > 0) ? nsplit : 1;
    const int s_len = n / zdim;
    attn_mfma<<<dim3(n / 16, 4, zdim), 256, 0, stream>>>(
        qb, kb, vb, out, opart, lpart, n, s_len, nsplit > 0 ? 1 : 0);

    ln_kernel<<<dim3(n), 256, 0, stream>>>(out, gamma, beta, opart, lpart, nsplit, n);
}